// Round 1
// baseline (1249.420 us; speedup 1.0000x reference)
//
#include <hip/hip_runtime.h>

// RiskGCN: 3-layer GCNConv (self-loops, sym deg^-1/2 norm) + mean pool + linear head.
// N=100000 nodes, E=1.6M edges, D=128, 256 graphs. All f32.

#define D 128

// ---------------- degree (incoming, excluding self-loop) ----------------
__global__ void k_degree(const int* __restrict__ dst, int E, int* __restrict__ degi) {
    int e = blockIdx.x * blockDim.x + threadIdx.x;
    if (e < E) atomicAdd(&degi[dst[e]], 1);
}

__global__ void k_dinv(const int* __restrict__ degi, float* __restrict__ dinv, int N) {
    int i = blockIdx.x * blockDim.x + threadIdx.x;
    if (i < N) dinv[i] = rsqrtf((float)(degi[i] + 1));   // +1 self-loop; always > 0
}

// ---------------- exclusive scan of degi -> row_start (3-kernel scan) ----------------
__global__ void k_scan1(const int* __restrict__ cnt, int N, int* __restrict__ bsum) {
    __shared__ int sdata[256];
    int t = threadIdx.x;
    int base = blockIdx.x * 1024 + t * 4;
    int s = 0;
#pragma unroll
    for (int j = 0; j < 4; j++) { int i = base + j; if (i < N) s += cnt[i]; }
    sdata[t] = s; __syncthreads();
    for (int off = 128; off > 0; off >>= 1) {
        if (t < off) sdata[t] += sdata[t + off];
        __syncthreads();
    }
    if (t == 0) bsum[blockIdx.x] = sdata[0];
}

__global__ void k_scan2(int* __restrict__ bsum, int nb) {
    if (threadIdx.x == 0) {
        int run = 0;
        for (int b = 0; b < nb; b++) { int v = bsum[b]; bsum[b] = run; run += v; }
    }
}

__global__ void k_scan3(const int* __restrict__ cnt, int N, const int* __restrict__ bofs,
                        int* __restrict__ row_start, int E) {
    __shared__ int sdata[256];
    int t = threadIdx.x;
    int base = blockIdx.x * 1024 + t * 4;
    int v[4]; int s = 0;
#pragma unroll
    for (int j = 0; j < 4; j++) { int i = base + j; v[j] = (i < N) ? cnt[i] : 0; s += v[j]; }
    sdata[t] = s; __syncthreads();
    // inclusive Hillis-Steele over 256 thread-sums
    for (int off = 1; off < 256; off <<= 1) {
        int x = (t >= off) ? sdata[t - off] : 0;
        __syncthreads();
        sdata[t] += x;
        __syncthreads();
    }
    int excl = (t == 0) ? 0 : sdata[t - 1];
    int run = bofs[blockIdx.x] + excl;
#pragma unroll
    for (int j = 0; j < 4; j++) {
        int i = base + j;
        if (i < N) row_start[i] = run;
        run += v[j];
    }
    if (blockIdx.x == 0 && t == 0) row_start[N] = E;
}

// ---------------- CSR fill (slot order nondeterministic; sum is f32-stable enough) ----------------
__global__ void k_fill(const int* __restrict__ src, const int* __restrict__ dst, int E,
                       const int* __restrict__ row_start, int* __restrict__ cursor,
                       int* __restrict__ csr_src) {
    int e = blockIdx.x * blockDim.x + threadIdx.x;
    if (e >= E) return;
    int d = dst[e];
    int pos = atomicAdd(&cursor[d], 1);
    csr_src[row_start[d] + pos] = src[e];
}

// ---------------- dense transform: out[N x 128] = in[N x 128] @ W[128 x 128] ----------------
// 256 thr = 4 waves/block; wave handles 8 rows; lane handles 2 cols (float2).
__global__ __launch_bounds__(256) void k_gemm(const float* __restrict__ in,
                                              const float* __restrict__ W,
                                              float* __restrict__ out, int N) {
    int wave = threadIdx.x >> 6, lane = threadIdx.x & 63;
    int row0 = (blockIdx.x * 4 + wave) * 8;
    int col = lane * 2;
    float acc0[8], acc1[8];
#pragma unroll
    for (int r = 0; r < 8; r++) { acc0[r] = 0.f; acc1[r] = 0.f; }
    if (row0 + 8 <= N) {
        for (int k = 0; k < D; k += 4) {
            float4 a[8];
#pragma unroll
            for (int r = 0; r < 8; r++)
                a[r] = *(const float4*)(in + (size_t)(row0 + r) * D + k);
#pragma unroll
            for (int j = 0; j < 4; j++) {
                float2 w = *(const float2*)(W + (size_t)(k + j) * D + col);
#pragma unroll
                for (int r = 0; r < 8; r++) {
                    float av = (j == 0) ? a[r].x : (j == 1) ? a[r].y : (j == 2) ? a[r].z : a[r].w;
                    acc0[r] = fmaf(av, w.x, acc0[r]);
                    acc1[r] = fmaf(av, w.y, acc1[r]);
                }
            }
        }
#pragma unroll
        for (int r = 0; r < 8; r++)
            *(float2*)(out + (size_t)(row0 + r) * D + col) = make_float2(acc0[r], acc1[r]);
    } else {
        for (int k = 0; k < D; k++) {
            float2 w = *(const float2*)(W + (size_t)k * D + col);
#pragma unroll
            for (int r = 0; r < 8; r++) {
                if (row0 + r < N) {
                    float av = in[(size_t)(row0 + r) * D + k];
                    acc0[r] = fmaf(av, w.x, acc0[r]);
                    acc1[r] = fmaf(av, w.y, acc1[r]);
                }
            }
        }
#pragma unroll
        for (int r = 0; r < 8; r++)
            if (row0 + r < N)
                *(float2*)(out + (size_t)(row0 + r) * D + col) = make_float2(acc0[r], acc1[r]);
    }
}

// ---------------- aggregation: out[i] = relu( sum_j norm*t[j] + dinv[i]^2*t[i] + b ) ----------------
// one wave per node; lane covers 2 cols.
__global__ __launch_bounds__(256) void k_agg(const float* __restrict__ t,
                                             const float* __restrict__ dinv,
                                             const int* __restrict__ row_start,
                                             const int* __restrict__ csr_src,
                                             const float* __restrict__ bias,
                                             float* __restrict__ out, int N) {
    int wave = threadIdx.x >> 6, lane = threadIdx.x & 63;
    int node = blockIdx.x * 4 + wave;
    if (node >= N) return;
    int col = lane * 2;
    float di = dinv[node];
    float2 v = *(const float2*)(t + (size_t)node * D + col);
    float a0 = v.x * di * di, a1 = v.y * di * di;
    int beg = row_start[node], end = row_start[node + 1];
    for (int e = beg; e < end; e++) {
        int s = csr_src[e];
        float nrm = dinv[s] * di;
        float2 u = *(const float2*)(t + (size_t)s * D + col);
        a0 = fmaf(nrm, u.x, a0);
        a1 = fmaf(nrm, u.y, a1);
    }
    a0 = fmaxf(a0 + bias[col], 0.f);
    a1 = fmaxf(a1 + bias[col + 1], 0.f);
    *(float2*)(out + (size_t)node * D + col) = make_float2(a0, a1);
}

// ---------------- mean pool per graph + head: out[g] = (mean h) @ Wh + bh ----------------
__global__ __launch_bounds__(128) void k_pool(const float* __restrict__ h,
                                              const int* __restrict__ batch, int N,
                                              const float* __restrict__ Wh,
                                              const float* __restrict__ bh,
                                              float* __restrict__ out) {
    int g = blockIdx.x;
    int c = threadIdx.x;  // 128 threads, one per feature
    // lower_bound(batch, key) on sorted batch
    int lo = 0, hi = N;
    while (lo < hi) { int m = (lo + hi) >> 1; if (batch[m] < g) lo = m + 1; else hi = m; }
    int beg = lo;
    lo = 0; hi = N;
    while (lo < hi) { int m = (lo + hi) >> 1; if (batch[m] < g + 1) lo = m + 1; else hi = m; }
    int endi = lo;
    float s = 0.f;
    for (int i = beg; i < endi; i++) s += h[(size_t)i * D + c];
    float cnt = (float)((endi - beg) > 0 ? (endi - beg) : 1);
    float p = s / cnt;
    __shared__ float r0[128], r1[128];
    r0[c] = p * Wh[c * 2 + 0];
    r1[c] = p * Wh[c * 2 + 1];
    __syncthreads();
    for (int off = 64; off > 0; off >>= 1) {
        if (c < off) { r0[c] += r0[c + off]; r1[c] += r1[c + off]; }
        __syncthreads();
    }
    if (c == 0) {
        out[g * 2 + 0] = r0[0] + bh[0];
        out[g * 2 + 1] = r1[0] + bh[1];
    }
}

extern "C" void kernel_launch(void* const* d_in, const int* in_sizes, int n_in,
                              void* d_out, int out_size, void* d_ws, size_t ws_size,
                              hipStream_t stream) {
    const float* x   = (const float*)d_in[0];
    const int* eidx  = (const int*)d_in[1];
    const int* batch = (const int*)d_in[2];
    const float* W1 = (const float*)d_in[3];
    const float* b1 = (const float*)d_in[4];
    const float* W2 = (const float*)d_in[5];
    const float* b2 = (const float*)d_in[6];
    const float* W3 = (const float*)d_in[7];
    const float* b3 = (const float*)d_in[8];
    const float* Wh = (const float*)d_in[9];
    const float* bh = (const float*)d_in[10];

    int E = in_sizes[1] / 2;
    int N = in_sizes[2];
    int ngraphs = out_size / 2;
    const int* src = eidx;
    const int* dst = eidx + E;

    char* ws = (char*)d_ws;
    size_t off = 0;
    auto alloc = [&](size_t bytes) -> void* {
        void* p = ws + off;
        off = (off + bytes + 255) & ~(size_t)255;
        return p;
    };
    float* H        = (float*)alloc((size_t)N * D * 4);
    float* T        = (float*)alloc((size_t)N * D * 4);
    int*   degi     = (int*)alloc((size_t)N * 4);
    float* dinv     = (float*)alloc((size_t)N * 4);
    int*   row_start= (int*)alloc((size_t)(N + 1) * 4);
    int*   cursor   = (int*)alloc((size_t)N * 4);
    int*   bofs     = (int*)alloc(4096);
    int*   csr_src  = (int*)alloc((size_t)E * 4);
    (void)ws_size;

    hipMemsetAsync(degi, 0, (size_t)N * 4, stream);
    hipMemsetAsync(cursor, 0, (size_t)N * 4, stream);

    k_degree<<<(E + 255) / 256, 256, 0, stream>>>(dst, E, degi);
    k_dinv<<<(N + 255) / 256, 256, 0, stream>>>(degi, dinv, N);

    int nb = (N + 1023) / 1024;
    k_scan1<<<nb, 256, 0, stream>>>(degi, N, bofs);
    k_scan2<<<1, 64, 0, stream>>>(bofs, nb);
    k_scan3<<<nb, 256, 0, stream>>>(degi, N, bofs, row_start, E);
    k_fill<<<(E + 255) / 256, 256, 0, stream>>>(src, dst, E, row_start, cursor, csr_src);

    int gemm_grid = (N + 31) / 32;
    int agg_grid = (N + 3) / 4;

    // layer 1
    k_gemm<<<gemm_grid, 256, 0, stream>>>(x, W1, T, N);
    k_agg<<<agg_grid, 256, 0, stream>>>(T, dinv, row_start, csr_src, b1, H, N);
    // layer 2
    k_gemm<<<gemm_grid, 256, 0, stream>>>(H, W2, T, N);
    k_agg<<<agg_grid, 256, 0, stream>>>(T, dinv, row_start, csr_src, b2, H, N);
    // layer 3
    k_gemm<<<gemm_grid, 256, 0, stream>>>(H, W3, T, N);
    k_agg<<<agg_grid, 256, 0, stream>>>(T, dinv, row_start, csr_src, b3, H, N);

    // pool + head
    k_pool<<<ngraphs, 128, 0, stream>>>(H, batch, N, Wh, bh, (float*)d_out);
}

// Round 2
// 684.829 us; speedup vs baseline: 1.8244x; 1.8244x over previous
//
#include <hip/hip_runtime.h>

// RiskGCN: 3-layer GCNConv (self-loops, sym deg^-1/2 norm) + mean pool + linear head.
// N=100000 nodes, E=1.6M edges, D=128, 256 graphs.
// Strategy: CSR build once; per layer GEMM(f32 in -> bf16 out) + CSR gather-agg
// (bf16 messages, f32 accumulate) fused with self-loop/bias/relu.

#define D 128

typedef unsigned int uint;
typedef unsigned short ushort;

__device__ __forceinline__ ushort f2bf(float f) {
    uint u = __float_as_uint(f);
    uint r = (u + 0x7fffu + ((u >> 16) & 1u)) >> 16;   // round-to-nearest-even
    return (ushort)r;
}

// ---------------- degree (incoming, excluding self-loop) ----------------
__global__ void k_degree(const int* __restrict__ dst, int E, int* __restrict__ degi) {
    int e = blockIdx.x * blockDim.x + threadIdx.x;
    if (e < E) atomicAdd(&degi[dst[e]], 1);
}

__global__ void k_dinv(const int* __restrict__ degi, float* __restrict__ dinv, int N) {
    int i = blockIdx.x * blockDim.x + threadIdx.x;
    if (i < N) dinv[i] = rsqrtf((float)(degi[i] + 1));   // +1 self-loop; always > 0
}

// ---------------- exclusive scan of degi -> row_start ----------------
__global__ void k_scan1(const int* __restrict__ cnt, int N, int* __restrict__ bsum) {
    __shared__ int sdata[256];
    int t = threadIdx.x;
    int base = blockIdx.x * 1024 + t * 4;
    int s = 0;
#pragma unroll
    for (int j = 0; j < 4; j++) { int i = base + j; if (i < N) s += cnt[i]; }
    sdata[t] = s; __syncthreads();
    for (int off = 128; off > 0; off >>= 1) {
        if (t < off) sdata[t] += sdata[t + off];
        __syncthreads();
    }
    if (t == 0) bsum[blockIdx.x] = sdata[0];
}

__global__ void k_scan2(int* __restrict__ bsum, int nb) {
    if (threadIdx.x == 0) {
        int run = 0;
        for (int b = 0; b < nb; b++) { int v = bsum[b]; bsum[b] = run; run += v; }
    }
}

__global__ void k_scan3(const int* __restrict__ cnt, int N, const int* __restrict__ bofs,
                        int* __restrict__ row_start, int E) {
    __shared__ int sdata[256];
    int t = threadIdx.x;
    int base = blockIdx.x * 1024 + t * 4;
    int v[4]; int s = 0;
#pragma unroll
    for (int j = 0; j < 4; j++) { int i = base + j; v[j] = (i < N) ? cnt[i] : 0; s += v[j]; }
    sdata[t] = s; __syncthreads();
    for (int off = 1; off < 256; off <<= 1) {
        int x = (t >= off) ? sdata[t - off] : 0;
        __syncthreads();
        sdata[t] += x;
        __syncthreads();
    }
    int excl = (t == 0) ? 0 : sdata[t - 1];
    int run = bofs[blockIdx.x] + excl;
#pragma unroll
    for (int j = 0; j < 4; j++) {
        int i = base + j;
        if (i < N) row_start[i] = run;
        run += v[j];
    }
    if (blockIdx.x == 0 && t == 0) row_start[N] = E;
}

// ---------------- CSR fill: pack (src, norm) per edge ----------------
__global__ void k_fill(const int* __restrict__ src, const int* __restrict__ dst, int E,
                       const int* __restrict__ row_start, int* __restrict__ cursor,
                       const float* __restrict__ dinv, int2* __restrict__ csr) {
    int e = blockIdx.x * blockDim.x + threadIdx.x;
    if (e >= E) return;
    int d = dst[e];
    int s = src[e];
    int pos = atomicAdd(&cursor[d], 1);
    float nrm = dinv[s] * dinv[d];
    csr[row_start[d] + pos] = make_int2(s, __float_as_int(nrm));
}

// ---------------- dense transform: out_bf16[N x 128] = in[N x 128] @ W[128 x 128] ----------------
// 256 thr = 4 waves; block covers 32 rows (wave: 8 rows); lane: 2 cols.
// A-tile staged in LDS (16 KB); A reads are wave-broadcast ds_read_b128.
__global__ __launch_bounds__(256) void k_gemm(const float* __restrict__ in,
                                              const float* __restrict__ W,
                                              ushort* __restrict__ out, int N) {
    __shared__ float As[32 * D];
    int t = threadIdx.x;
    int rowb = blockIdx.x * 32;

    // stage 32x128 f32 tile: 1024 float4, 4 per thread, coalesced
    const float4* src4 = (const float4*)in;
#pragma unroll
    for (int i = 0; i < 4; i++) {
        int f4 = i * 256 + t;               // float4 index in tile
        int grow = rowb + (f4 >> 5);        // 32 float4 per row
        float4 v = make_float4(0.f, 0.f, 0.f, 0.f);
        if (grow < N) v = src4[(size_t)rowb * 32 + f4];
        ((float4*)As)[f4] = v;
    }
    __syncthreads();

    int wave = t >> 6, lane = t & 63;
    int col = lane * 2;
    const float* Wc = W + col;
    const float* Arow = As + (wave * 8) * D;

    float acc0[8], acc1[8];
#pragma unroll
    for (int r = 0; r < 8; r++) { acc0[r] = 0.f; acc1[r] = 0.f; }

    for (int k4 = 0; k4 < D / 4; k4++) {
        int k = k4 * 4;
        float2 w0 = *(const float2*)(Wc + (size_t)(k + 0) * D);
        float2 w1 = *(const float2*)(Wc + (size_t)(k + 1) * D);
        float2 w2 = *(const float2*)(Wc + (size_t)(k + 2) * D);
        float2 w3 = *(const float2*)(Wc + (size_t)(k + 3) * D);
#pragma unroll
        for (int r = 0; r < 8; r++) {
            float4 a = *(const float4*)(Arow + r * D + k);
            acc0[r] = fmaf(a.x, w0.x, acc0[r]);
            acc0[r] = fmaf(a.y, w1.x, acc0[r]);
            acc0[r] = fmaf(a.z, w2.x, acc0[r]);
            acc0[r] = fmaf(a.w, w3.x, acc0[r]);
            acc1[r] = fmaf(a.x, w0.y, acc1[r]);
            acc1[r] = fmaf(a.y, w1.y, acc1[r]);
            acc1[r] = fmaf(a.z, w2.y, acc1[r]);
            acc1[r] = fmaf(a.w, w3.y, acc1[r]);
        }
    }

#pragma unroll
    for (int r = 0; r < 8; r++) {
        int grow = rowb + wave * 8 + r;
        if (grow < N) {
            ushort2 o;
            o.x = f2bf(acc0[r]);
            o.y = f2bf(acc1[r]);
            *(ushort2*)(out + (size_t)grow * D + col) = o;
        }
    }
}

// ---------------- aggregation: H[i] = relu( sum_j nrm_j*T[j] + di^2*T[i] + b ) ----------------
// one wave per node; lane covers 2 cols (one u32 = 2 bf16). f32 accumulate.
__global__ __launch_bounds__(256) void k_agg(const ushort* __restrict__ T,
                                             const float* __restrict__ dinv,
                                             const int* __restrict__ row_start,
                                             const int2* __restrict__ csr,
                                             const float* __restrict__ bias,
                                             float* __restrict__ out, int N) {
    int wave = threadIdx.x >> 6, lane = threadIdx.x & 63;
    int node = blockIdx.x * 4 + wave;
    if (node >= N) return;
    int col = lane * 2;

    float di = dinv[node];
    uint vs = *(const uint*)(T + (size_t)node * D + col);
    float sw = di * di;
    float a0 = sw * __uint_as_float(vs << 16);
    float a1 = sw * __uint_as_float(vs & 0xffff0000u);

    int e = row_start[node], end = row_start[node + 1];
    for (; e + 4 <= end; e += 4) {
        int2 c0 = csr[e + 0];
        int2 c1 = csr[e + 1];
        int2 c2 = csr[e + 2];
        int2 c3 = csr[e + 3];
        uint v0 = *(const uint*)(T + (size_t)c0.x * D + col);
        uint v1 = *(const uint*)(T + (size_t)c1.x * D + col);
        uint v2 = *(const uint*)(T + (size_t)c2.x * D + col);
        uint v3 = *(const uint*)(T + (size_t)c3.x * D + col);
        float n0 = __int_as_float(c0.y), n1 = __int_as_float(c1.y);
        float n2 = __int_as_float(c2.y), n3 = __int_as_float(c3.y);
        a0 = fmaf(n0, __uint_as_float(v0 << 16), a0);
        a1 = fmaf(n0, __uint_as_float(v0 & 0xffff0000u), a1);
        a0 = fmaf(n1, __uint_as_float(v1 << 16), a0);
        a1 = fmaf(n1, __uint_as_float(v1 & 0xffff0000u), a1);
        a0 = fmaf(n2, __uint_as_float(v2 << 16), a0);
        a1 = fmaf(n2, __uint_as_float(v2 & 0xffff0000u), a1);
        a0 = fmaf(n3, __uint_as_float(v3 << 16), a0);
        a1 = fmaf(n3, __uint_as_float(v3 & 0xffff0000u), a1);
    }
    for (; e < end; e++) {
        int2 c = csr[e];
        uint v = *(const uint*)(T + (size_t)c.x * D + col);
        float n = __int_as_float(c.y);
        a0 = fmaf(n, __uint_as_float(v << 16), a0);
        a1 = fmaf(n, __uint_as_float(v & 0xffff0000u), a1);
    }

    a0 = fmaxf(a0 + bias[col], 0.f);
    a1 = fmaxf(a1 + bias[col + 1], 0.f);
    *(float2*)(out + (size_t)node * D + col) = make_float2(a0, a1);
}

// ---------------- mean pool per graph + head ----------------
__global__ __launch_bounds__(128) void k_pool(const float* __restrict__ h,
                                              const int* __restrict__ batch, int N,
                                              const float* __restrict__ Wh,
                                              const float* __restrict__ bh,
                                              float* __restrict__ out) {
    int g = blockIdx.x;
    int c = threadIdx.x;  // 128 threads, one per feature
    int lo = 0, hi = N;
    while (lo < hi) { int m = (lo + hi) >> 1; if (batch[m] < g) lo = m + 1; else hi = m; }
    int beg = lo;
    lo = 0; hi = N;
    while (lo < hi) { int m = (lo + hi) >> 1; if (batch[m] < g + 1) lo = m + 1; else hi = m; }
    int endi = lo;
    float s = 0.f;
    for (int i = beg; i < endi; i++) s += h[(size_t)i * D + c];
    float cnt = (float)((endi - beg) > 0 ? (endi - beg) : 1);
    float p = s / cnt;
    __shared__ float r0[128], r1[128];
    r0[c] = p * Wh[c * 2 + 0];
    r1[c] = p * Wh[c * 2 + 1];
    __syncthreads();
    for (int off = 64; off > 0; off >>= 1) {
        if (c < off) { r0[c] += r0[c + off]; r1[c] += r1[c + off]; }
        __syncthreads();
    }
    if (c == 0) {
        out[g * 2 + 0] = r0[0] + bh[0];
        out[g * 2 + 1] = r1[0] + bh[1];
    }
}

extern "C" void kernel_launch(void* const* d_in, const int* in_sizes, int n_in,
                              void* d_out, int out_size, void* d_ws, size_t ws_size,
                              hipStream_t stream) {
    const float* x   = (const float*)d_in[0];
    const int* eidx  = (const int*)d_in[1];
    const int* batch = (const int*)d_in[2];
    const float* W1 = (const float*)d_in[3];
    const float* b1 = (const float*)d_in[4];
    const float* W2 = (const float*)d_in[5];
    const float* b2 = (const float*)d_in[6];
    const float* W3 = (const float*)d_in[7];
    const float* b3 = (const float*)d_in[8];
    const float* Wh = (const float*)d_in[9];
    const float* bh = (const float*)d_in[10];

    int E = in_sizes[1] / 2;
    int N = in_sizes[2];
    int ngraphs = out_size / 2;
    const int* src = eidx;
    const int* dst = eidx + E;

    char* ws = (char*)d_ws;
    size_t off = 0;
    auto alloc = [&](size_t bytes) -> void* {
        void* p = ws + off;
        off = (off + bytes + 255) & ~(size_t)255;
        return p;
    };
    float*  H        = (float*)alloc((size_t)N * D * 4);
    ushort* T        = (ushort*)alloc((size_t)N * D * 2);
    int*    degi     = (int*)alloc((size_t)N * 4);
    float*  dinv     = (float*)alloc((size_t)N * 4);
    int*    row_start= (int*)alloc((size_t)(N + 1) * 4);
    int*    cursor   = (int*)alloc((size_t)N * 4);
    int*    bofs     = (int*)alloc(4096);
    int2*   csr      = (int2*)alloc((size_t)E * 8);
    (void)ws_size;

    hipMemsetAsync(degi, 0, (size_t)N * 4, stream);
    hipMemsetAsync(cursor, 0, (size_t)N * 4, stream);

    k_degree<<<(E + 255) / 256, 256, 0, stream>>>(dst, E, degi);
    k_dinv<<<(N + 255) / 256, 256, 0, stream>>>(degi, dinv, N);

    int nb = (N + 1023) / 1024;
    k_scan1<<<nb, 256, 0, stream>>>(degi, N, bofs);
    k_scan2<<<1, 64, 0, stream>>>(bofs, nb);
    k_scan3<<<nb, 256, 0, stream>>>(degi, N, bofs, row_start, E);
    k_fill<<<(E + 255) / 256, 256, 0, stream>>>(src, dst, E, row_start, cursor, dinv, csr);

    int gemm_grid = (N + 31) / 32;
    int agg_grid = (N + 3) / 4;

    // layer 1
    k_gemm<<<gemm_grid, 256, 0, stream>>>(x, W1, T, N);
    k_agg<<<agg_grid, 256, 0, stream>>>(T, dinv, row_start, csr, b1, H, N);
    // layer 2
    k_gemm<<<gemm_grid, 256, 0, stream>>>(H, W2, T, N);
    k_agg<<<agg_grid, 256, 0, stream>>>(T, dinv, row_start, csr, b2, H, N);
    // layer 3
    k_gemm<<<gemm_grid, 256, 0, stream>>>(H, W3, T, N);
    k_agg<<<agg_grid, 256, 0, stream>>>(T, dinv, row_start, csr, b3, H, N);

    // pool + head
    k_pool<<<ngraphs, 128, 0, stream>>>(H, batch, N, Wh, bh, (float*)d_out);
}